// Round 1
// baseline (135.914 us; speedup 1.0000x reference)
//
#include <hip/hip_runtime.h>

// Problem constants (fixed by the reference):
//   T = B*C = 4 trees, N = 262144 = 2^18 nodes/tree, HW = 1048576 = 2^20 pixels/tree
#define NT 4
#define NN 262144
#define NMASK (NN - 1)
#define HW 1048576
// 3-level solve hierarchy: v[i] = c[i] + v[parent[i]], parent[i] < i.
//   level A: [0, KA)    walk to root            (avg depth ln(4096)  ~ 8.3)
//   level B: [KA, KB)   walk until < KA, fold   (avg steps ln(16)    ~ 2.0)
//   level C: [KB, NN)   walk until < KB, fold   (avg steps ~0.85)
// Total walk lane-gathers ~2.3M vs 4.3M for the old single-level KPRE=16K.
#define KA 4096
#define KB 65536

// XCD-locality swizzle: blocks are dispatched round-robin across 8 XCDs
// (heuristic, perf-only). Map tree = (b&7)>>1 so each XCD touches exactly one
// tree's arrays (2MB cmb + 1MB v), which fits its 4MB L2.
#define SWIZ(b, tree, chunk)                \
    int tree  = ((b) & 7) >> 1;             \
    int chunk = (((b) >> 3) << 1) | ((b) & 1);

// ---------------------------------------------------------------------------
// K1: build packed node records {parent, c} where
//   c[i] = sigmoid(clip(1000*(attr[i]-thr), -12, 12)) * (levels[i]-levels[parent[i]])
//   c[root]=levels[root], parent[root]=0
// One 8B record per node -> each walk step is a single dwordx2 gather.
// ---------------------------------------------------------------------------
__global__ __launch_bounds__(256) void k_build(const float* __restrict__ attr,
                                               const float* __restrict__ levels,
                                               const float* __restrict__ thr,
                                               const int* __restrict__ parent,
                                               int2* __restrict__ cmb) {
    SWIZ(blockIdx.x, tree, chunk)            // 4096 blocks, 1024 chunks/tree
    int n = chunk * 256 + threadIdx.x;       // node within tree
    int i = (tree << 18) + n;
    int p = parent[i] & NMASK;               // parent (mask = OOB guard)
    float lv = levels[i];
    float lp = levels[(tree << 18) | p];     // random gather, tree-local (L2)
    float z = 1000.0f * (attr[i] - thr[0]);
    z = fminf(fmaxf(z, -12.0f), 12.0f);
    float s = 1.0f / (1.0f + __expf(-z));
    float c = s * (lv - lp);
    if (n == 0) { c = lv; p = 0; }           // root: c = levels[0], self-parent
    cmb[i] = make_int2(p, __float_as_int(c));
}

// ---------------------------------------------------------------------------
// K2 (level A): v[i] for i < KA by walking to the root. All ancestors of a
// node are below it, so chains stay inside the first KA records = 32KB/tree
// (L2/L1-resident). Avg depth ln(KA)~8.3, probabilistic max ~25 (cap 64 is a
// hang-guard). Only 64 blocks -> pure latency phase, ~3us.
// ---------------------------------------------------------------------------
__global__ __launch_bounds__(256) void k_prefix(const int2* __restrict__ cmb,
                                                float* __restrict__ v) {
    SWIZ(blockIdx.x, tree, chunk)            // 64 blocks, 16 chunks/tree
    int node = chunk * 256 + threadIdx.x;    // 0..KA-1
    const int2* ctree = cmb + (tree << 18);
    float acc = 0.0f;
    int cur = node;
    bool alive = true;
    for (int it = 0; it < 64 && __any(alive); ++it) {
        if (alive) {
            int2 rec = ctree[cur];
            acc += __int_as_float(rec.y);    // includes levels[0] at the root
            if (cur == 0) alive = false;
            else cur = rec.x;                // rec.x < cur < KA
        }
    }
    v[(tree << 18) + node] = acc;
}

// ---------------------------------------------------------------------------
// K3 (level B): nodes [KA, KB). Walk until the chain drops below KA, then add
// the precomputed level-A value. Expected steps ln(KB/KA)=2.77 averaged-down
// to ~1.96 over the interval. 1 chain/thread, 960 blocks (good occupancy).
// ---------------------------------------------------------------------------
__global__ __launch_bounds__(256) void k_walkB(const int2* __restrict__ cmb,
                                               float* __restrict__ v) {
    SWIZ(blockIdx.x, tree, chunk)            // 960 blocks, 240 chunks/tree
    int node = KA + chunk * 256 + threadIdx.x;
    const int2*  ctree = cmb + (tree << 18);
    const float* vtree = v + (tree << 18);
    float acc = 0.0f;
    int cur = node;
    bool alive = true;
    for (int it = 0; it < 64 && __any(alive); ++it) {
        if (alive) {
            int2 rec = ctree[cur];           // one 8B gather per step, L2-hit
            acc += __int_as_float(rec.y);
            int nxt = rec.x;
            if (nxt < KA) {                  // terminate: fold level-A value
                acc += vtree[nxt];           // 16KB/tree -> L1/L2-hit
                alive = false;
            } else {
                cur = nxt;
            }
        }
    }
    v[(tree << 18) + node] = acc;
}

// ---------------------------------------------------------------------------
// K4 (level C): nodes [KB, NN). Walk until below KB (expected ~0.85 steps),
// fold the level-B/A value. 4 chains/thread for MLP, 768 blocks.
// ---------------------------------------------------------------------------
__global__ __launch_bounds__(256) void k_walkC(const int2* __restrict__ cmb,
                                               float* __restrict__ v) {
    SWIZ(blockIdx.x, tree, chunk)            // 768 blocks, 192 chunks/tree
    int base = KB + chunk * 1024;            // node offset within tree
    const int2*  ctree = cmb + (tree << 18);
    const float* vtree = v + (tree << 18);

    int   cur[4];
    float acc[4];
    int alive = 0xF;
#pragma unroll
    for (int k = 0; k < 4; ++k) {
        cur[k] = base + threadIdx.x + k * 256;
        acc[k] = 0.0f;
    }
    for (int it = 0; it < 64 && __any(alive); ++it) {
#pragma unroll
        for (int k = 0; k < 4; ++k) {
            if (alive & (1 << k)) {
                int2 rec = ctree[cur[k]];    // one 8B gather per step, L2-hit
                acc[k] += __int_as_float(rec.y);
                int nxt = rec.x;
                if (nxt < KB) {              // terminate: fold in prefix value
                    acc[k] += vtree[nxt];    // 256KB/tree -> L2-hit
                    alive &= ~(1 << k);
                } else {
                    cur[k] = nxt;
                }
            }
        }
    }
#pragma unroll
    for (int k = 0; k < 4; ++k)
        v[(tree << 18) + base + threadIdx.x + k * 256] = acc[k];  // coalesced
}

// ---------------------------------------------------------------------------
// K5: pixel gather  y[t][p] = v[t][pixel_to_node[t][p]], int4/float4 vectorized.
// Swizzled so each XCD gathers from one tree's 1MB v array.
// ---------------------------------------------------------------------------
__global__ __launch_bounds__(256) void k_pix(const float* __restrict__ v,
                                             const int* __restrict__ p2n,
                                             float* __restrict__ y) {
    SWIZ(blockIdx.x, tree, chunk)            // 4096 blocks, 1024 chunks/tree
    int i = (tree << 18) + chunk * 256 + threadIdx.x;  // int4 index
    int4 idx = ((const int4*)p2n)[i];
    const float* vt = v + (tree << 18);
    float4 o;
    o.x = vt[idx.x & NMASK];
    o.y = vt[idx.y & NMASK];
    o.z = vt[idx.z & NMASK];
    o.w = vt[idx.w & NMASK];
    ((float4*)y)[i] = o;
}

extern "C" void kernel_launch(void* const* d_in, const int* in_sizes, int n_in,
                              void* d_out, int out_size, void* d_ws, size_t ws_size,
                              hipStream_t stream) {
    // setup_inputs order: 0:x (unused), 1:attr_norm, 2:levels, 3:thr, 4:parent, 5:pixel_to_node
    const float* attr   = (const float*)d_in[1];
    const float* levels = (const float*)d_in[2];
    const float* thr    = (const float*)d_in[3];
    const int*   parent = (const int*)d_in[4];
    const int*   p2n    = (const int*)d_in[5];
    float*       y      = (float*)d_out;

    // workspace: cmb = NT*NN int2 (8 MB), v = NT*NN float (4 MB)
    int2*  cmb = (int2*)d_ws;
    float* v   = (float*)((char*)d_ws + (size_t)NT * NN * sizeof(int2));

    k_build <<<NT * NN / 256, 256, 0, stream>>>(attr, levels, thr, parent, cmb);
    k_prefix<<<NT * KA / 256, 256, 0, stream>>>(cmb, v);
    k_walkB <<<NT * (KB - KA) / 256, 256, 0, stream>>>(cmb, v);
    k_walkC <<<NT * (NN - KB) / 1024, 256, 0, stream>>>(cmb, v);
    k_pix   <<<NT * HW / 4 / 256, 256, 0, stream>>>(v, p2n, y);
}